// Round 1
// baseline (516.988 us; speedup 1.0000x reference)
//
#include <hip/hip_runtime.h>
#include <hip/hip_fp16.h>

#define Bc 4
#define Sc 2048
#define Dc 768
#define Hc 12
#define DKc 64

typedef _Float16 f16;
typedef __attribute__((ext_vector_type(8))) _Float16 f16x8;
typedef __attribute__((ext_vector_type(4))) _Float16 f16x4;
typedef __attribute__((ext_vector_type(4))) float f32x4;

static __device__ __forceinline__ f32x4 mfma16(f16x8 a, f16x8 b, f32x4 c) {
  return __builtin_amdgcn_mfma_f32_16x16x32_f16(a, b, c, 0, 0, 0);
}

// ---------------- f32 -> f16 conversion ----------------
__global__ __launch_bounds__(256) void cvt_f32_f16(const float* __restrict__ in,
                                                   f16* __restrict__ out, int n4) {
  int i = blockIdx.x * blockDim.x + threadIdx.x;
  if (i >= n4) return;
  float4 v = reinterpret_cast<const float4*>(in)[i];
  f16x4 o;
  o[0] = (f16)v.x; o[1] = (f16)v.y; o[2] = (f16)v.z; o[3] = (f16)v.w;
  reinterpret_cast<f16x4*>(out)[i] = o;
}

// ---------------- generic MFMA GEMM:  out = A @ Bw^T (+bias) ----------------
// A: [M x K] row-major f16.  Bw: [N x K] row-major f16 (so B-operand[k][n]=Bw[n][k]).
// MODE 0: dst f16 row-major [M][N], + bias
// MODE 1: dst f16 V-transposed: dst[(b*N + n)*Sc + s], b=row>>11, s=row&2047, + bias
// MODE 2: dst f32 row-major [M][N], + bias
// MODE 3: dst f32 row-major [M][N] * scale, batched via blockIdx.z (no bias)
template <int MODE>
__global__ __launch_bounds__(256) void gemm16(
    const f16* __restrict__ A, const f16* __restrict__ Bw,
    const float* __restrict__ bias, void* __restrict__ dst,
    int M, int N, int K, long sAz, long sBz, long sDz, float scale) {
  const int tid  = threadIdx.x;
  const int lane = tid & 63;
  const int wv   = tid >> 6;
  const int wr = wv >> 1, wc = wv & 1;
  const int l15 = lane & 15, lg = lane >> 4;
  const long m0 = (long)blockIdx.x * 64;
  const long n0 = (long)blockIdx.y * 64;
  const f16* Ab = A + (long)blockIdx.z * sAz;
  const f16* Bb = Bw + (long)blockIdx.z * sBz;

  __shared__ f16 As[64][40];
  __shared__ f16 Bs[64][40];

  f32x4 acc[2][2] = {};

  const int lrow = tid >> 2;        // 0..63
  const int lcol = (tid & 3) << 3;  // 0,8,16,24

  for (int k0 = 0; k0 < K; k0 += 32) {
    f16x8 av = *reinterpret_cast<const f16x8*>(Ab + (m0 + lrow) * (long)K + k0 + lcol);
    f16x8 bv = *reinterpret_cast<const f16x8*>(Bb + (n0 + lrow) * (long)K + k0 + lcol);
    *reinterpret_cast<f16x8*>(&As[lrow][lcol]) = av;
    *reinterpret_cast<f16x8*>(&Bs[lrow][lcol]) = bv;
    __syncthreads();
    f16x8 af[2], bf[2];
#pragma unroll
    for (int mi = 0; mi < 2; ++mi)
      af[mi] = *reinterpret_cast<const f16x8*>(&As[wr * 32 + mi * 16 + l15][lg * 8]);
#pragma unroll
    for (int ni = 0; ni < 2; ++ni)
      bf[ni] = *reinterpret_cast<const f16x8*>(&Bs[wc * 32 + ni * 16 + l15][lg * 8]);
#pragma unroll
    for (int mi = 0; mi < 2; ++mi)
#pragma unroll
      for (int ni = 0; ni < 2; ++ni)
        acc[mi][ni] = mfma16(af[mi], bf[ni], acc[mi][ni]);
    __syncthreads();
  }

#pragma unroll
  for (int mi = 0; mi < 2; ++mi) {
#pragma unroll
    for (int ni = 0; ni < 2; ++ni) {
      const long col = n0 + wc * 32 + ni * 16 + l15;
      const float bv = (MODE == 3) ? 0.0f : bias[col];
#pragma unroll
      for (int j = 0; j < 4; ++j) {
        const long row = m0 + wr * 32 + mi * 16 + lg * 4 + j;
        float val = acc[mi][ni][j] + bv;
        if (MODE == 0) {
          ((f16*)dst)[row * N + col] = (f16)val;
        } else if (MODE == 1) {
          const long b = row >> 11, s = row & 2047;
          ((f16*)dst)[(b * N + col) * (long)Sc + s] = (f16)val;
        } else if (MODE == 2) {
          ((float*)dst)[row * N + col] = val;
        } else {
          float* dp = (float*)dst + (long)blockIdx.z * sDz;
          dp[row * N + col] = val * scale;
        }
      }
    }
  }
}

// ---------------- flash attention (1 wave / block, 16 q-rows) ----------------
// Q,K: [B,S,D] f16 (head h at cols h*64..h*64+63).  Vt: [B,D,S] f16.  ctx: [B,S,D] f16.
__global__ __launch_bounds__(64) void attn16(const f16* __restrict__ Q,
                                             const f16* __restrict__ Km,
                                             const f16* __restrict__ Vt,
                                             f16* __restrict__ ctx) {
  const int lane = threadIdx.x;
  const int l15 = lane & 15, lg = lane >> 4;
  const int bid = blockIdx.x;
  const int qt = bid & 127;            // S/16 = 128
  const int h  = (bid >> 7) % Hc;
  const int b  = bid / (128 * Hc);
  const int q0 = qt * 16;

  f16x8 qa[2];
  {
    const f16* qp = Q + ((long)(b * Sc + q0 + l15)) * Dc + h * DKc + lg * 8;
    qa[0] = *reinterpret_cast<const f16x8*>(qp);
    qa[1] = *reinterpret_cast<const f16x8*>(qp + 32);
  }

  float m_run[4], l_run[4];
  f32x4 o[4] = {};
#pragma unroll
  for (int j = 0; j < 4; ++j) { m_run[j] = -1e30f; l_run[j] = 0.f; }

  __shared__ f16 Plds[16][40];

  const f16* Kb = Km + (long)b * Sc * Dc + h * DKc;
  const f16* Vb = Vt + ((long)b * Dc + h * DKc) * Sc;

  for (int kv0 = 0; kv0 < Sc; kv0 += 32) {
    f32x4 sc[2];
#pragma unroll
    for (int t = 0; t < 2; ++t) {
      const f16* kp = Kb + (long)(kv0 + t * 16 + l15) * Dc + lg * 8;
      f16x8 k0 = *reinterpret_cast<const f16x8*>(kp);
      f16x8 k1 = *reinterpret_cast<const f16x8*>(kp + 32);
      f32x4 s = {};
      s = mfma16(qa[0], k0, s);
      s = mfma16(qa[1], k1, s);
      sc[t] = s;
    }
    float p0a[4], p1a[4], alpha[4];
#pragma unroll
    for (int j = 0; j < 4; ++j) {
      float v0 = sc[0][j] * 0.125f, v1 = sc[1][j] * 0.125f;
      float mx = fmaxf(v0, v1);
      mx = fmaxf(mx, __shfl_xor(mx, 1));
      mx = fmaxf(mx, __shfl_xor(mx, 2));
      mx = fmaxf(mx, __shfl_xor(mx, 4));
      mx = fmaxf(mx, __shfl_xor(mx, 8));
      float mn = fmaxf(m_run[j], mx);
      float al = __expf(m_run[j] - mn);
      float p0 = __expf(v0 - mn);
      float p1 = __expf(v1 - mn);
      float ps = p0 + p1;
      ps += __shfl_xor(ps, 1);
      ps += __shfl_xor(ps, 2);
      ps += __shfl_xor(ps, 4);
      ps += __shfl_xor(ps, 8);
      l_run[j] = l_run[j] * al + ps;
      m_run[j] = mn;
      alpha[j] = al;
      p0a[j] = p0; p1a[j] = p1;
    }
#pragma unroll
    for (int c = 0; c < 4; ++c)
#pragma unroll
      for (int j = 0; j < 4; ++j) o[c][j] *= alpha[j];

    __syncthreads();  // WAR: previous iteration's P reads done before overwrite
#pragma unroll
    for (int j = 0; j < 4; ++j) {
      Plds[lg * 4 + j][l15]      = (f16)p0a[j];
      Plds[lg * 4 + j][16 + l15] = (f16)p1a[j];
    }
    __syncthreads();
    f16x8 pa = *reinterpret_cast<const f16x8*>(&Plds[l15][lg * 8]);
#pragma unroll
    for (int c = 0; c < 4; ++c) {
      const f16* vp = Vb + (long)(c * 16 + l15) * Sc + kv0 + lg * 8;
      f16x8 vf = *reinterpret_cast<const f16x8*>(vp);
      o[c] = mfma16(pa, vf, o[c]);
    }
  }
#pragma unroll
  for (int c = 0; c < 4; ++c) {
#pragma unroll
    for (int j = 0; j < 4; ++j) {
      float val = o[c][j] / l_run[j];
      long row = q0 + lg * 4 + j;
      ctx[((long)(b * Sc) + row) * Dc + h * DKc + c * 16 + l15] = (f16)val;
    }
  }
}

extern "C" void kernel_launch(void* const* d_in, const int* in_sizes, int n_in,
                              void* d_out, int out_size, void* d_ws, size_t ws_size,
                              hipStream_t stream) {
  (void)in_sizes; (void)n_in; (void)out_size; (void)ws_size;
  const float* z    = (const float*)d_in[0];
  const float* wq_w = (const float*)d_in[1];
  const float* wq_b = (const float*)d_in[2];
  const float* wk_w = (const float*)d_in[3];
  const float* wk_b = (const float*)d_in[4];
  const float* wv_w = (const float*)d_in[5];
  const float* wv_b = (const float*)d_in[6];
  const float* fc_w = (const float*)d_in[7];
  const float* fc_b = (const float*)d_in[8];
  float* out = (float*)d_out;

  char* ws = (char*)d_ws;
  size_t off = 0;
  auto alloc = [&](size_t bytes) -> void* {
    void* p = (void*)(ws + off);
    off += (bytes + 255) & ~(size_t)255;
    return p;
  };
  const size_t zdb = (size_t)Bc * Sc * Dc * sizeof(f16);   // 12.6 MB
  const size_t wdb = (size_t)Dc * Dc * sizeof(f16);        // 1.2 MB
  f16* zb  = (f16*)alloc(zdb);
  f16* wqb = (f16*)alloc(wdb);
  f16* wkb = (f16*)alloc(wdb);
  f16* wvb = (f16*)alloc(wdb);
  f16* fcb = (f16*)alloc(wdb);
  f16* Qb  = (f16*)alloc(zdb);
  f16* Kb  = (f16*)alloc(zdb);
  f16* Vt  = (f16*)alloc(zdb);
  f16* Cx  = zb;  // alias: zb is dead after the three projection GEMMs

  const int nz4 = Bc * Sc * Dc / 4;  // 1572864
  const int nw4 = Dc * Dc / 4;       // 147456
  cvt_f32_f16<<<nz4 / 256, 256, 0, stream>>>(z, zb, nz4);
  cvt_f32_f16<<<nw4 / 256, 256, 0, stream>>>(wq_w, wqb, nw4);
  cvt_f32_f16<<<nw4 / 256, 256, 0, stream>>>(wk_w, wkb, nw4);
  cvt_f32_f16<<<nw4 / 256, 256, 0, stream>>>(wv_w, wvb, nw4);
  cvt_f32_f16<<<nw4 / 256, 256, 0, stream>>>(fc_w, fcb, nw4);

  dim3 gproj(Bc * Sc / 64, Dc / 64, 1);  // 128 x 12
  gemm16<0><<<gproj, 256, 0, stream>>>(zb, wqb, wq_b, Qb, Bc * Sc, Dc, Dc, 0, 0, 0, 1.f);
  gemm16<0><<<gproj, 256, 0, stream>>>(zb, wkb, wk_b, Kb, Bc * Sc, Dc, Dc, 0, 0, 0, 1.f);
  gemm16<1><<<gproj, 256, 0, stream>>>(zb, wvb, wv_b, Vt, Bc * Sc, Dc, Dc, 0, 0, 0, 1.f);

  // avg_weights = (Qfull @ Kfull^T) / (temp*H), temp=8, H=12
  dim3 gavg(Sc / 64, Sc / 64, Bc);  // 32 x 32 x 4
  gemm16<3><<<gavg, 256, 0, stream>>>(Qb, Kb, nullptr, out + (size_t)Bc * Sc * Dc,
                                      Sc, Sc, Dc, (long)Sc * Dc, (long)Sc * Dc,
                                      (long)Sc * Sc, 1.0f / 96.0f);

  attn16<<<Bc * Hc * (Sc / 16), 64, 0, stream>>>(Qb, Kb, Vt, Cx);

  gemm16<2><<<gproj, 256, 0, stream>>>(Cx, fcb, fc_b, out, Bc * Sc, Dc, Dc, 0, 0, 0, 1.f);
}

// Round 2
// 287.328 us; speedup vs baseline: 1.7993x; 1.7993x over previous
//
#include <hip/hip_runtime.h>
#include <hip/hip_fp16.h>

#define Bc 4
#define Sc 2048
#define Dc 768
#define Hc 12
#define DKc 64

typedef _Float16 f16;
typedef __attribute__((ext_vector_type(8))) _Float16 f16x8;
typedef __attribute__((ext_vector_type(4))) _Float16 f16x4;
typedef __attribute__((ext_vector_type(4))) float f32x4;

static __device__ __forceinline__ f32x4 mfma16(f16x8 a, f16x8 b, f32x4 c) {
  return __builtin_amdgcn_mfma_f32_16x16x32_f16(a, b, c, 0, 0, 0);
}

// ---------------- f32 -> f16 conversion ----------------
__global__ __launch_bounds__(256) void cvt_f32_f16(const float* __restrict__ in,
                                                   f16* __restrict__ out, int n4) {
  int i = blockIdx.x * blockDim.x + threadIdx.x;
  if (i >= n4) return;
  float4 v = reinterpret_cast<const float4*>(in)[i];
  f16x4 o;
  o[0] = (f16)v.x; o[1] = (f16)v.y; o[2] = (f16)v.z; o[3] = (f16)v.w;
  reinterpret_cast<f16x4*>(out)[i] = o;
}

// ---------------- generic MFMA GEMM:  out = A @ Bw^T (+bias) ----------------
// MODE 0: dst f16 row-major [M][N], + bias
// MODE 1: dst f16 V-transposed: dst[(b*N + n)*Sc + s], b=row>>11, s=row&2047, + bias
// MODE 2: dst f32 row-major [M][N], + bias
// MODE 3: dst f32 row-major [M][N] * scale, batched via blockIdx.z (no bias)
template <int MODE>
__global__ __launch_bounds__(256) void gemm16(
    const f16* __restrict__ A, const f16* __restrict__ Bw,
    const float* __restrict__ bias, void* __restrict__ dst,
    int M, int N, int K, long sAz, long sBz, long sDz, float scale) {
  const int tid  = threadIdx.x;
  const int lane = tid & 63;
  const int wv   = tid >> 6;
  const int wr = wv >> 1, wc = wv & 1;
  const int l15 = lane & 15, lg = lane >> 4;
  const long m0 = (long)blockIdx.x * 64;
  const long n0 = (long)blockIdx.y * 64;
  const f16* Ab = A + (long)blockIdx.z * sAz;
  const f16* Bb = Bw + (long)blockIdx.z * sBz;

  __shared__ f16 As[64][40];
  __shared__ f16 Bs[64][40];

  f32x4 acc[2][2] = {};

  const int lrow = tid >> 2;        // 0..63
  const int lcol = (tid & 3) << 3;  // 0,8,16,24

  for (int k0 = 0; k0 < K; k0 += 32) {
    f16x8 av = *reinterpret_cast<const f16x8*>(Ab + (m0 + lrow) * (long)K + k0 + lcol);
    f16x8 bv = *reinterpret_cast<const f16x8*>(Bb + (n0 + lrow) * (long)K + k0 + lcol);
    *reinterpret_cast<f16x8*>(&As[lrow][lcol]) = av;
    *reinterpret_cast<f16x8*>(&Bs[lrow][lcol]) = bv;
    __syncthreads();
    f16x8 af[2], bf[2];
#pragma unroll
    for (int mi = 0; mi < 2; ++mi)
      af[mi] = *reinterpret_cast<const f16x8*>(&As[wr * 32 + mi * 16 + l15][lg * 8]);
#pragma unroll
    for (int ni = 0; ni < 2; ++ni)
      bf[ni] = *reinterpret_cast<const f16x8*>(&Bs[wc * 32 + ni * 16 + l15][lg * 8]);
#pragma unroll
    for (int mi = 0; mi < 2; ++mi)
#pragma unroll
      for (int ni = 0; ni < 2; ++ni)
        acc[mi][ni] = mfma16(af[mi], bf[ni], acc[mi][ni]);
    __syncthreads();
  }

#pragma unroll
  for (int mi = 0; mi < 2; ++mi) {
#pragma unroll
    for (int ni = 0; ni < 2; ++ni) {
      const long col = n0 + wc * 32 + ni * 16 + l15;
      const float bv = (MODE == 3) ? 0.0f : bias[col];
#pragma unroll
      for (int j = 0; j < 4; ++j) {
        const long row = m0 + wr * 32 + mi * 16 + lg * 4 + j;
        float val = acc[mi][ni][j] + bv;
        if (MODE == 0) {
          ((f16*)dst)[row * N + col] = (f16)val;
        } else if (MODE == 1) {
          const long b = row >> 11, s = row & 2047;
          ((f16*)dst)[(b * N + col) * (long)Sc + s] = (f16)val;
        } else if (MODE == 2) {
          ((float*)dst)[row * N + col] = val;
        } else {
          float* dp = (float*)dst + (long)blockIdx.z * sDz;
          dp[row * N + col] = val * scale;
        }
      }
    }
  }
}

// ---------------- flash attention: 4 waves/block, 64 q-rows, KVBLK=64 -------
// Swapped QK^T (D[kv][q] in regs -> near-lane-local softmax), O computed as
// O^T = V^T @ P^T. K/V staged in LDS (pad 72 -> conflict-free fragment reads),
// T14 async-split staging (issue loads early, ds_write after barrier).
__global__ __launch_bounds__(256) void attn4(const f16* __restrict__ Q,
                                             const f16* __restrict__ Km,
                                             const f16* __restrict__ Vt,
                                             f16* __restrict__ ctx) {
  const int tid = threadIdx.x;
  const int lane = tid & 63;
  const int w = tid >> 6;
  const int l15 = lane & 15, lg = lane >> 4;
  const int bid = blockIdx.x;
  const int qt = bid & 31;              // S/64 = 32 q-tiles
  const int h  = (bid >> 5) % Hc;
  const int b  = bid / (32 * Hc);
  const int q0 = qt * 64;

  __shared__ f16 Ks[64][72];
  __shared__ f16 Vs[64][72];
  __shared__ f16 Ps[4][16][72];

  // Q fragment = B-operand of swapped QK: B[k=d][n=q], lane holds q = l15.
  f16x8 qf[2];
  {
    const f16* qp = Q + ((long)(b * Sc + q0 + w * 16 + l15)) * Dc + h * DKc + lg * 8;
    qf[0] = *reinterpret_cast<const f16x8*>(qp);
    qf[1] = *reinterpret_cast<const f16x8*>(qp + 32);
  }

  const int srow = tid >> 2;           // 0..63
  const int scol = (tid & 3) * 16;     // 0,16,32,48
  const f16* Kb = Km + (long)(b * Sc) * Dc + h * DKc;    // + kv*Dc + d
  const f16* Vb = Vt + ((long)(b * Dc + h * DKc)) * Sc;  // + dk*Sc + kv

  float m_run = -1e30f, l_run = 0.f;
  f32x4 o[4] = {};

  // prologue: stage tile 0
  {
    const f16* kp = Kb + (long)srow * Dc + scol;
    const f16* vp = Vb + (long)srow * Sc + scol;
    f16x8 k0 = *reinterpret_cast<const f16x8*>(kp);
    f16x8 k1 = *reinterpret_cast<const f16x8*>(kp + 8);
    f16x8 v0 = *reinterpret_cast<const f16x8*>(vp);
    f16x8 v1 = *reinterpret_cast<const f16x8*>(vp + 8);
    *reinterpret_cast<f16x8*>(&Ks[srow][scol])     = k0;
    *reinterpret_cast<f16x8*>(&Ks[srow][scol + 8]) = k1;
    *reinterpret_cast<f16x8*>(&Vs[srow][scol])     = v0;
    *reinterpret_cast<f16x8*>(&Vs[srow][scol + 8]) = v1;
  }
  __syncthreads();

  for (int kv0 = 0; kv0 < Sc; kv0 += 64) {
    const bool pf = (kv0 + 64) < Sc;
    f16x8 kr0, kr1, vr0, vr1;
    if (pf) {  // T14: issue next-tile loads early; ds_write after barrier
      const f16* kp = Kb + (long)(kv0 + 64 + srow) * Dc + scol;
      const f16* vp = Vb + (long)srow * Sc + (kv0 + 64) + scol;
      kr0 = *reinterpret_cast<const f16x8*>(kp);
      kr1 = *reinterpret_cast<const f16x8*>(kp + 8);
      vr0 = *reinterpret_cast<const f16x8*>(vp);
      vr1 = *reinterpret_cast<const f16x8*>(vp + 8);
    }

    // QK^T swapped: sc[t] = K_t @ Q^T -> D[kv][q], lane: q=l15, kv=t*16+lg*4+j
    f32x4 sc[4];
#pragma unroll
    for (int t = 0; t < 4; ++t) {
      f32x4 s = {};
      s = mfma16(*reinterpret_cast<const f16x8*>(&Ks[t * 16 + l15][lg * 8]), qf[0], s);
      s = mfma16(*reinterpret_cast<const f16x8*>(&Ks[t * 16 + l15][32 + lg * 8]), qf[1], s);
      sc[t] = s;
    }

    // online softmax: 15 in-reg fmax + 2 shfls (combine the 4 lane-groups)
    float mx = -1e30f;
#pragma unroll
    for (int t = 0; t < 4; ++t)
#pragma unroll
      for (int j = 0; j < 4; ++j) mx = fmaxf(mx, sc[t][j]);
    mx *= 0.125f;
    mx = fmaxf(mx, __shfl_xor(mx, 16));
    mx = fmaxf(mx, __shfl_xor(mx, 32));
    const float mn = fmaxf(m_run, mx);
    const float al = __expf(m_run - mn);
    float ps = 0.f;
    f16x4 pp[4];
#pragma unroll
    for (int t = 0; t < 4; ++t) {
#pragma unroll
      for (int j = 0; j < 4; ++j) {
        float p = __expf(sc[t][j] * 0.125f - mn);
        pp[t][j] = (f16)p;
        ps += p;
      }
    }
    ps += __shfl_xor(ps, 16);
    ps += __shfl_xor(ps, 32);
    l_run = l_run * al + ps;
    m_run = mn;
#pragma unroll
    for (int c = 0; c < 4; ++c)
#pragma unroll
      for (int j = 0; j < 4; ++j) o[c][j] *= al;

    // P^T regs -> Ps[w][q][kv] (per-wave buffer, wave-internal ordering only)
#pragma unroll
    for (int t = 0; t < 4; ++t)
      *reinterpret_cast<f16x4*>(&Ps[w][l15][t * 16 + lg * 4]) = pp[t];
    asm volatile("s_waitcnt lgkmcnt(0)" ::: "memory");
    __builtin_amdgcn_sched_barrier(0);

    // PV: O^T += V^T @ P^T   (A = V^T rows dk, B = P^T cols q)
    f16x8 pa0 = *reinterpret_cast<const f16x8*>(&Ps[w][l15][lg * 8]);
    f16x8 pa1 = *reinterpret_cast<const f16x8*>(&Ps[w][l15][32 + lg * 8]);
#pragma unroll
    for (int c = 0; c < 4; ++c) {
      o[c] = mfma16(*reinterpret_cast<const f16x8*>(&Vs[c * 16 + l15][lg * 8]), pa0, o[c]);
      o[c] = mfma16(*reinterpret_cast<const f16x8*>(&Vs[c * 16 + l15][32 + lg * 8]), pa1, o[c]);
    }

    if (pf) {
      __syncthreads();  // all waves done reading Ks/Vs
      *reinterpret_cast<f16x8*>(&Ks[srow][scol])     = kr0;
      *reinterpret_cast<f16x8*>(&Ks[srow][scol + 8]) = kr1;
      *reinterpret_cast<f16x8*>(&Vs[srow][scol])     = vr0;
      *reinterpret_cast<f16x8*>(&Vs[srow][scol + 8]) = vr1;
      __syncthreads();  // new tile visible
    }
  }

  // epilogue: o[c][j] = O^T[dk = c*16 + lg*4 + j][q = l15]
  const float inv = 1.0f / l_run;
  const long row = q0 + w * 16 + l15;
  f16* cp = ctx + ((long)(b * Sc) + row) * Dc + h * DKc;
#pragma unroll
  for (int c = 0; c < 4; ++c) {
    f16x4 ov;
#pragma unroll
    for (int j = 0; j < 4; ++j) ov[j] = (f16)(o[c][j] * inv);
    *reinterpret_cast<f16x4*>(cp + c * 16 + lg * 4) = ov;
  }
}

extern "C" void kernel_launch(void* const* d_in, const int* in_sizes, int n_in,
                              void* d_out, int out_size, void* d_ws, size_t ws_size,
                              hipStream_t stream) {
  (void)in_sizes; (void)n_in; (void)out_size; (void)ws_size;
  const float* z    = (const float*)d_in[0];
  const float* wq_w = (const float*)d_in[1];
  const float* wq_b = (const float*)d_in[2];
  const float* wk_w = (const float*)d_in[3];
  const float* wk_b = (const float*)d_in[4];
  const float* wv_w = (const float*)d_in[5];
  const float* wv_b = (const float*)d_in[6];
  const float* fc_w = (const float*)d_in[7];
  const float* fc_b = (const float*)d_in[8];
  float* out = (float*)d_out;

  char* ws = (char*)d_ws;
  size_t off = 0;
  auto alloc = [&](size_t bytes) -> void* {
    void* p = (void*)(ws + off);
    off += (bytes + 255) & ~(size_t)255;
    return p;
  };
  const size_t zdb = (size_t)Bc * Sc * Dc * sizeof(f16);   // 12.6 MB
  const size_t wdb = (size_t)Dc * Dc * sizeof(f16);        // 1.2 MB
  f16* zb  = (f16*)alloc(zdb);
  f16* wqb = (f16*)alloc(wdb);
  f16* wkb = (f16*)alloc(wdb);
  f16* wvb = (f16*)alloc(wdb);
  f16* fcb = (f16*)alloc(wdb);
  f16* Qb  = (f16*)alloc(zdb);
  f16* Kb  = (f16*)alloc(zdb);
  f16* Vt  = (f16*)alloc(zdb);
  f16* Cx  = zb;  // alias: zb is dead after the three projection GEMMs

  const int nz4 = Bc * Sc * Dc / 4;  // 1572864
  const int nw4 = Dc * Dc / 4;       // 147456
  cvt_f32_f16<<<nz4 / 256, 256, 0, stream>>>(z, zb, nz4);
  cvt_f32_f16<<<nw4 / 256, 256, 0, stream>>>(wq_w, wqb, nw4);
  cvt_f32_f16<<<nw4 / 256, 256, 0, stream>>>(wk_w, wkb, nw4);
  cvt_f32_f16<<<nw4 / 256, 256, 0, stream>>>(wv_w, wvb, nw4);
  cvt_f32_f16<<<nw4 / 256, 256, 0, stream>>>(fc_w, fcb, nw4);

  dim3 gproj(Bc * Sc / 64, Dc / 64, 1);  // 128 x 12
  gemm16<0><<<gproj, 256, 0, stream>>>(zb, wqb, wq_b, Qb, Bc * Sc, Dc, Dc, 0, 0, 0, 1.f);
  gemm16<0><<<gproj, 256, 0, stream>>>(zb, wkb, wk_b, Kb, Bc * Sc, Dc, Dc, 0, 0, 0, 1.f);
  gemm16<1><<<gproj, 256, 0, stream>>>(zb, wvb, wv_b, Vt, Bc * Sc, Dc, Dc, 0, 0, 0, 1.f);

  // avg_weights = (Qfull @ Kfull^T) / (temp*H), temp=8, H=12
  dim3 gavg(Sc / 64, Sc / 64, Bc);  // 32 x 32 x 4
  gemm16<3><<<gavg, 256, 0, stream>>>(Qb, Kb, nullptr, out + (size_t)Bc * Sc * Dc,
                                      Sc, Sc, Dc, (long)Sc * Dc, (long)Sc * Dc,
                                      (long)Sc * Sc, 1.0f / 96.0f);

  attn4<<<Bc * Hc * (Sc / 64), 256, 0, stream>>>(Qb, Kb, Vt, Cx);

  gemm16<2><<<gproj, 256, 0, stream>>>(Cx, fcb, fc_b, out, Bc * Sc, Dc, Dc, 0, 0, 0, 1.f);
}

// Round 3
// 246.601 us; speedup vs baseline: 2.0965x; 1.1652x over previous
//
#include <hip/hip_runtime.h>
#include <hip/hip_fp16.h>

#define Bc 4
#define Sc 2048
#define Dc 768
#define Hc 12
#define DKc 64

typedef _Float16 f16;
typedef __attribute__((ext_vector_type(8))) _Float16 f16x8;
typedef __attribute__((ext_vector_type(4))) _Float16 f16x4;
typedef __attribute__((ext_vector_type(4))) float f32x4;

static __device__ __forceinline__ f32x4 mfma16(f16x8 a, f16x8 b, f32x4 c) {
  return __builtin_amdgcn_mfma_f32_16x16x32_f16(a, b, c, 0, 0, 0);
}

// async global->LDS, 16B per lane. LDS dest is wave-uniform base + lane*16.
#define GLD16(g, l)                                              \
  __builtin_amdgcn_global_load_lds(                              \
      (const __attribute__((address_space(1))) void*)(g),        \
      (__attribute__((address_space(3))) void*)(l), 16, 0, 0)

// ---------------- f32 -> f16 conversion ----------------
__global__ __launch_bounds__(256) void cvt_f32_f16(const float* __restrict__ in,
                                                   f16* __restrict__ out, int n4) {
  int i = blockIdx.x * blockDim.x + threadIdx.x;
  if (i >= n4) return;
  float4 v = reinterpret_cast<const float4*>(in)[i];
  f16x4 o;
  o[0] = (f16)v.x; o[1] = (f16)v.y; o[2] = (f16)v.z; o[3] = (f16)v.w;
  reinterpret_cast<f16x4*>(out)[i] = o;
}

// ------------- 128x128 MFMA GEMM (m97 structure):  out = A @ Bw^T -----------
// A: [M x K] row-major f16.  Bw: [N x K] row-major f16.
// MODE 0: dst f16 row-major [M][N], + bias
// MODE 1: dst f16 V-transposed: dst[(b*N + n)*Sc + s], b=row>>11, s=row&2047, + bias
// MODE 2: dst f32 row-major [M][N], + bias
// MODE 3: dst f32 row-major [M][N] * scale, batched via blockIdx.z (no bias)
template <int MODE>
__global__ __launch_bounds__(256) void gemm128(
    const f16* __restrict__ A, const f16* __restrict__ Bw,
    const float* __restrict__ bias, void* __restrict__ dst,
    int M, int N, int K, long sAz, long sBz, long sDz, float scale) {
  const int tid  = threadIdx.x;
  const int lane = tid & 63;
  const int w    = tid >> 6;       // 0..3
  const int wr = w >> 1, wc = w & 1;
  const int l15 = lane & 15, lg = lane >> 4;
  const long m0 = (long)blockIdx.x * 128;
  const long n0 = (long)blockIdx.y * 128;
  const f16* Ab = A + (long)blockIdx.z * sAz + m0 * K;
  const f16* Bb = Bw + (long)blockIdx.z * sBz + n0 * K;

  __shared__ f16 As[128][32];
  __shared__ f16 Bs[128][32];

  f32x4 acc[4][4] = {};

  // staging: wave w covers LDS rows [w*32, w*32+32); 2 gload_lds per matrix.
  // lane l -> row sub (l>>2), col chunk (l&3)*8; LDS byte = base + l*16.
  const int srow = lane >> 2;
  const int scol = (lane & 3) * 8;
  const f16* Ag = Ab + (long)(w * 32 + srow) * K + scol;
  const f16* Bg = Bb + (long)(w * 32 + srow) * K + scol;
  f16* As0 = &As[w * 32][0];
  f16* As1 = &As[w * 32 + 16][0];
  f16* Bs0 = &Bs[w * 32][0];
  f16* Bs1 = &Bs[w * 32 + 16][0];
  const long k16 = (long)16 * K;

  for (int k0 = 0; k0 < K; k0 += 32) {
    GLD16(Ag + k0, As0);
    GLD16(Ag + k0 + k16, As1);
    GLD16(Bg + k0, Bs0);
    GLD16(Bg + k0 + k16, Bs1);
    __syncthreads();  // compiler drains vmcnt(0) before barrier
    f16x8 af[4], bf[4];
#pragma unroll
    for (int i = 0; i < 4; ++i) {
      af[i] = *reinterpret_cast<const f16x8*>(&As[wr * 64 + i * 16 + l15][lg * 8]);
      bf[i] = *reinterpret_cast<const f16x8*>(&Bs[wc * 64 + i * 16 + l15][lg * 8]);
    }
#pragma unroll
    for (int mi = 0; mi < 4; ++mi)
#pragma unroll
      for (int ni = 0; ni < 4; ++ni)
        acc[mi][ni] = mfma16(af[mi], bf[ni], acc[mi][ni]);
    __syncthreads();  // WAR: all reads done before next gload_lds
  }

#pragma unroll
  for (int mi = 0; mi < 4; ++mi) {
#pragma unroll
    for (int ni = 0; ni < 4; ++ni) {
      const long col = n0 + wc * 64 + ni * 16 + l15;
      const float bv = (MODE == 3) ? 0.0f : bias[col];
#pragma unroll
      for (int j = 0; j < 4; ++j) {
        const long row = m0 + wr * 64 + mi * 16 + lg * 4 + j;
        float val = acc[mi][ni][j] + bv;
        if (MODE == 0) {
          ((f16*)dst)[row * N + col] = (f16)val;
        } else if (MODE == 1) {
          const long b = row >> 11, s = row & 2047;
          ((f16*)dst)[(b * N + col) * (long)Sc + s] = (f16)val;
        } else if (MODE == 2) {
          ((float*)dst)[row * N + col] = val;
        } else {
          float* dp = (float*)dst + (long)blockIdx.z * sDz;
          dp[row * N + col] = val * scale;
        }
      }
    }
  }
}

// -------- flash attention: 8 waves/block, 128 q-rows, KVBLK=64 --------------
// Swapped QK^T (lane holds 16 kv-scores of one q), exp2-domain online softmax
// with defer-max (T13), O^T = V^T @ P^T, T14 async staging, T5 setprio.
__global__ __launch_bounds__(512) void attn8(const f16* __restrict__ Q,
                                             const f16* __restrict__ Km,
                                             const f16* __restrict__ Vt,
                                             f16* __restrict__ ctx) {
  const int tid = threadIdx.x;
  const int lane = tid & 63;
  const int w = tid >> 6;              // 0..7
  const int l15 = lane & 15, lg = lane >> 4;
  const int bid = blockIdx.x;
  const int qt = bid & 15;             // S/128 = 16 q-tiles
  const int h  = (bid >> 4) % Hc;
  const int b  = bid / (16 * Hc);
  const int q0 = qt * 128 + w * 16;

  __shared__ f16 Ks[64][72];
  __shared__ f16 Vs[64][72];
  __shared__ f16 Ps[8][16][72];

  // Q fragment = B-operand of swapped QK: lane holds q-col = l15.
  f16x8 qf[2];
  {
    const f16* qp = Q + ((long)(b * Sc + q0 + l15)) * Dc + h * DKc + lg * 8;
    qf[0] = *reinterpret_cast<const f16x8*>(qp);
    qf[1] = *reinterpret_cast<const f16x8*>(qp + 32);
  }

  const int srow = tid >> 3;           // 0..63 (512 threads)
  const int scol = (tid & 7) * 8;
  const f16* Kb = Km + (long)(b * Sc) * Dc + h * DKc;    // + kv*Dc + d
  const f16* Vb = Vt + ((long)(b * Dc + h * DKc)) * Sc;  // + dk*Sc + kv

  const float c2 = 0.18033688011f;     // log2(e) / temp, temp = 8
  float m2 = -1e30f, l_run = 0.f;
  f32x4 o[4] = {};

  // prologue: stage tile 0
  *reinterpret_cast<f16x8*>(&Ks[srow][scol]) =
      *reinterpret_cast<const f16x8*>(Kb + (long)srow * Dc + scol);
  *reinterpret_cast<f16x8*>(&Vs[srow][scol]) =
      *reinterpret_cast<const f16x8*>(Vb + (long)srow * Sc + scol);
  __syncthreads();

  for (int kv0 = 0; kv0 < Sc; kv0 += 64) {
    const bool pf = (kv0 + 64) < Sc;
    f16x8 kr, vr;
    if (pf) {  // T14: issue next-tile loads early; ds_write after barrier
      kr = *reinterpret_cast<const f16x8*>(Kb + (long)(kv0 + 64 + srow) * Dc + scol);
      vr = *reinterpret_cast<const f16x8*>(Vb + (long)srow * Sc + kv0 + 64 + scol);
    }

    // swapped QK^T: sc[t] -> D[kv][q], lane: q = l15, kv = t*16 + lg*4 + j
    f32x4 sc[4];
    __builtin_amdgcn_s_setprio(1);
#pragma unroll
    for (int t = 0; t < 4; ++t) {
      f32x4 s = {};
      s = mfma16(*reinterpret_cast<const f16x8*>(&Ks[t * 16 + l15][lg * 8]), qf[0], s);
      s = mfma16(*reinterpret_cast<const f16x8*>(&Ks[t * 16 + l15][32 + lg * 8]), qf[1], s);
      sc[t] = s;
    }
    __builtin_amdgcn_s_setprio(0);

    // online softmax, log2 domain, defer-max (THR = 8 nats = 11.544 bits)
    float mx = sc[0][0];
#pragma unroll
    for (int t = 0; t < 4; ++t)
#pragma unroll
      for (int j = 0; j < 4; ++j) mx = fmaxf(mx, sc[t][j]);
    const float mx2 = mx * c2;
    float al = 1.0f;
    if (!__all(mx2 <= m2 + 11.544f)) {
      float g = fmaxf(mx2, __shfl_xor(mx2, 16));
      g = fmaxf(g, __shfl_xor(g, 32));
      const float mn2 = fmaxf(m2, g);
      al = __builtin_amdgcn_exp2f(m2 - mn2);
      m2 = mn2;
#pragma unroll
      for (int c = 0; c < 4; ++c)
#pragma unroll
        for (int j = 0; j < 4; ++j) o[c][j] *= al;
    }
    float ps = 0.f;
    f16x4 pp[4];
#pragma unroll
    for (int t = 0; t < 4; ++t)
#pragma unroll
      for (int j = 0; j < 4; ++j) {
        float p = __builtin_amdgcn_exp2f(__builtin_fmaf(sc[t][j], c2, -m2));
        pp[t][j] = (f16)p;
        ps += p;
      }
    ps += __shfl_xor(ps, 16);
    ps += __shfl_xor(ps, 32);
    l_run = l_run * al + ps;

    // P^T regs -> Ps[w][q][kv] (per-wave buffer, wave-internal ordering only)
#pragma unroll
    for (int t = 0; t < 4; ++t)
      *reinterpret_cast<f16x4*>(&Ps[w][l15][t * 16 + lg * 4]) = pp[t];
    asm volatile("s_waitcnt lgkmcnt(0)" ::: "memory");
    __builtin_amdgcn_sched_barrier(0);

    // PV: O^T += V^T @ P^T
    f16x8 pa0 = *reinterpret_cast<const f16x8*>(&Ps[w][l15][lg * 8]);
    f16x8 pa1 = *reinterpret_cast<const f16x8*>(&Ps[w][l15][32 + lg * 8]);
    __builtin_amdgcn_s_setprio(1);
#pragma unroll
    for (int c = 0; c < 4; ++c) {
      o[c] = mfma16(*reinterpret_cast<const f16x8*>(&Vs[c * 16 + l15][lg * 8]), pa0, o[c]);
      o[c] = mfma16(*reinterpret_cast<const f16x8*>(&Vs[c * 16 + l15][32 + lg * 8]), pa1, o[c]);
    }
    __builtin_amdgcn_s_setprio(0);

    if (pf) {
      __syncthreads();  // all waves done reading Ks/Vs
      *reinterpret_cast<f16x8*>(&Ks[srow][scol]) = kr;
      *reinterpret_cast<f16x8*>(&Vs[srow][scol]) = vr;
      __syncthreads();  // new tile visible
    }
  }

  // epilogue: o[c][j] = O^T[dk = c*16 + lg*4 + j][q = l15]
  const float inv = 1.0f / l_run;
  f16* cp = ctx + ((long)(b * Sc) + q0 + l15) * Dc + h * DKc;
#pragma unroll
  for (int c = 0; c < 4; ++c) {
    f16x4 ov;
#pragma unroll
    for (int j = 0; j < 4; ++j) ov[j] = (f16)(o[c][j] * inv);
    *reinterpret_cast<f16x4*>(cp + c * 16 + lg * 4) = ov;
  }
}

extern "C" void kernel_launch(void* const* d_in, const int* in_sizes, int n_in,
                              void* d_out, int out_size, void* d_ws, size_t ws_size,
                              hipStream_t stream) {
  (void)in_sizes; (void)n_in; (void)out_size; (void)ws_size;
  const float* z    = (const float*)d_in[0];
  const float* wq_w = (const float*)d_in[1];
  const float* wq_b = (const float*)d_in[2];
  const float* wk_w = (const float*)d_in[3];
  const float* wk_b = (const float*)d_in[4];
  const float* wv_w = (const float*)d_in[5];
  const float* wv_b = (const float*)d_in[6];
  const float* fc_w = (const float*)d_in[7];
  const float* fc_b = (const float*)d_in[8];
  float* out = (float*)d_out;

  char* ws = (char*)d_ws;
  size_t off = 0;
  auto alloc = [&](size_t bytes) -> void* {
    void* p = (void*)(ws + off);
    off += (bytes + 255) & ~(size_t)255;
    return p;
  };
  const size_t zdb = (size_t)Bc * Sc * Dc * sizeof(f16);   // 12.6 MB
  const size_t wdb = (size_t)Dc * Dc * sizeof(f16);        // 1.2 MB
  f16* zb  = (f16*)alloc(zdb);
  f16* wqb = (f16*)alloc(wdb);
  f16* wkb = (f16*)alloc(wdb);
  f16* wvb = (f16*)alloc(wdb);
  f16* fcb = (f16*)alloc(wdb);
  f16* Qb  = (f16*)alloc(zdb);
  f16* Kb  = (f16*)alloc(zdb);
  f16* Vt  = (f16*)alloc(zdb);
  f16* Cx  = zb;  // alias: zb is dead after the three projection GEMMs

  const int nz4 = Bc * Sc * Dc / 4;  // 1572864
  const int nw4 = Dc * Dc / 4;       // 147456
  cvt_f32_f16<<<nz4 / 256, 256, 0, stream>>>(z, zb, nz4);
  cvt_f32_f16<<<nw4 / 256, 256, 0, stream>>>(wq_w, wqb, nw4);
  cvt_f32_f16<<<nw4 / 256, 256, 0, stream>>>(wk_w, wkb, nw4);
  cvt_f32_f16<<<nw4 / 256, 256, 0, stream>>>(wv_w, wvb, nw4);
  cvt_f32_f16<<<nw4 / 256, 256, 0, stream>>>(fc_w, fcb, nw4);

  dim3 gproj(Bc * Sc / 128, Dc / 128, 1);  // 64 x 6
  gemm128<0><<<gproj, 256, 0, stream>>>(zb, wqb, wq_b, Qb, Bc * Sc, Dc, Dc, 0, 0, 0, 1.f);
  gemm128<0><<<gproj, 256, 0, stream>>>(zb, wkb, wk_b, Kb, Bc * Sc, Dc, Dc, 0, 0, 0, 1.f);
  gemm128<1><<<gproj, 256, 0, stream>>>(zb, wvb, wv_b, Vt, Bc * Sc, Dc, Dc, 0, 0, 0, 1.f);

  // avg_weights = (Qfull @ Kfull^T) / (temp*H), temp=8, H=12
  dim3 gavg(Sc / 128, Sc / 128, Bc);  // 16 x 16 x 4
  gemm128<3><<<gavg, 256, 0, stream>>>(Qb, Kb, nullptr, out + (size_t)Bc * Sc * Dc,
                                       Sc, Sc, Dc, (long)Sc * Dc, (long)Sc * Dc,
                                       (long)Sc * Sc, 1.0f / 96.0f);

  attn8<<<Bc * Hc * (Sc / 128), 512, 0, stream>>>(Qb, Kb, Vt, Cx);

  gemm128<2><<<gproj, 256, 0, stream>>>(Cx, fcb, fc_b, out, Bc * Sc, Dc, Dc, 0, 0, 0, 1.f);
}

// Round 4
// 221.840 us; speedup vs baseline: 2.3305x; 1.1116x over previous
//
#include <hip/hip_runtime.h>
#include <hip/hip_fp16.h>

#define Bc 4
#define Sc 2048
#define Dc 768
#define Hc 12
#define DKc 64

typedef _Float16 f16;
typedef __attribute__((ext_vector_type(8))) _Float16 f16x8;
typedef __attribute__((ext_vector_type(4))) _Float16 f16x4;
typedef __attribute__((ext_vector_type(4))) float f32x4;

static __device__ __forceinline__ f32x4 mfma16(f16x8 a, f16x8 b, f32x4 c) {
  return __builtin_amdgcn_mfma_f32_16x16x32_f16(a, b, c, 0, 0, 0);
}

// async global->LDS, 16B per lane. LDS dest is wave-uniform base + lane*16.
#define GLD16(g, l)                                              \
  __builtin_amdgcn_global_load_lds(                              \
      (const __attribute__((address_space(1))) void*)(g),        \
      (__attribute__((address_space(3))) void*)(l), 16, 0, 0)

// T2 XOR swizzle: row stride 128B, byte col ^ ((row&7)<<4).  colB in [0,128).
#define SWZ(row, colB) (((row) << 7) + ((colB) ^ (((row) & 7) << 4)))

// ---------------- fused f32 -> f16 conversion (5 segments) ----------------
__global__ __launch_bounds__(256) void cvt5(
    const float* __restrict__ z, const float* __restrict__ w0,
    const float* __restrict__ w1, const float* __restrict__ w2,
    const float* __restrict__ w3, f16* __restrict__ oz, f16* __restrict__ o0,
    f16* __restrict__ o1, f16* __restrict__ o2, f16* __restrict__ o3) {
  const int bid = blockIdx.x;
  const float* in;
  f16* out;
  int i0;
  if (bid < 6144)      { in = z;  out = oz; i0 = bid * 256; }
  else if (bid < 6720) { in = w0; out = o0; i0 = (bid - 6144) * 256; }
  else if (bid < 7296) { in = w1; out = o1; i0 = (bid - 6720) * 256; }
  else if (bid < 7872) { in = w2; out = o2; i0 = (bid - 7296) * 256; }
  else                 { in = w3; out = o3; i0 = (bid - 7872) * 256; }
  const int i = i0 + threadIdx.x;
  float4 v = reinterpret_cast<const float4*>(in)[i];
  f16x4 o;
  o[0] = (f16)v.x; o[1] = (f16)v.y; o[2] = (f16)v.z; o[3] = (f16)v.w;
  reinterpret_cast<f16x4*>(out)[i] = o;
}

// ------------- 128x128 MFMA GEMM body (m97 structure) -----------------------
// Shared by the fused QKV kernel and the fc/avg kernels.
#define GEMM_CORE(Ab, Bb, K)                                                   \
  __shared__ f16 As[128][32];                                                  \
  __shared__ f16 Bs[128][32];                                                  \
  f32x4 acc[4][4] = {};                                                        \
  const int srow = lane >> 2;                                                  \
  const int scol = (lane & 3) * 8;                                             \
  const f16* Ag = (Ab) + (long)(w * 32 + srow) * (K) + scol;                   \
  const f16* Bg = (Bb) + (long)(w * 32 + srow) * (K) + scol;                   \
  f16* As0 = &As[w * 32][0];                                                   \
  f16* As1 = &As[w * 32 + 16][0];                                              \
  f16* Bs0 = &Bs[w * 32][0];                                                   \
  f16* Bs1 = &Bs[w * 32 + 16][0];                                              \
  const long k16 = (long)16 * (K);                                             \
  for (int k0 = 0; k0 < (K); k0 += 32) {                                       \
    GLD16(Ag + k0, As0);                                                       \
    GLD16(Ag + k0 + k16, As1);                                                 \
    GLD16(Bg + k0, Bs0);                                                       \
    GLD16(Bg + k0 + k16, Bs1);                                                 \
    __syncthreads();                                                           \
    f16x8 af[4], bf[4];                                                        \
    _Pragma("unroll") for (int i = 0; i < 4; ++i) {                            \
      af[i] = *reinterpret_cast<const f16x8*>(&As[wr * 64 + i * 16 + l15][lg * 8]); \
      bf[i] = *reinterpret_cast<const f16x8*>(&Bs[wc * 64 + i * 16 + l15][lg * 8]); \
    }                                                                          \
    _Pragma("unroll") for (int mi = 0; mi < 4; ++mi)                           \
      _Pragma("unroll") for (int ni = 0; ni < 4; ++ni)                         \
        acc[mi][ni] = mfma16(af[mi], bf[ni], acc[mi][ni]);                     \
    __syncthreads();                                                           \
  }

// Fused QKV projection: grid (M/128, 18). blockIdx.y: 0-5 Q, 6-11 K, 12-17 V.
__global__ __launch_bounds__(256) void gemm_qkv(
    const f16* __restrict__ zb, const f16* __restrict__ wq,
    const f16* __restrict__ wk, const f16* __restrict__ wv,
    const float* __restrict__ bq, const float* __restrict__ bk,
    const float* __restrict__ bv, f16* __restrict__ Qb, f16* __restrict__ Kb,
    f16* __restrict__ Vt) {
  const int tid = threadIdx.x;
  const int lane = tid & 63;
  const int w = tid >> 6;
  const int wr = w >> 1, wc = w & 1;
  const int l15 = lane & 15, lg = lane >> 4;
  const int sel = blockIdx.y / 6;
  const long m0 = (long)blockIdx.x * 128;
  const long n0 = (long)(blockIdx.y % 6) * 128;
  const f16* Bw = sel == 0 ? wq : sel == 1 ? wk : wv;
  const float* bias = sel == 0 ? bq : sel == 1 ? bk : bv;
  const f16* Ab = zb + m0 * Dc;
  const f16* Bb = Bw + n0 * Dc;

  GEMM_CORE(Ab, Bb, Dc)

  f16* dq = sel == 0 ? Qb : Kb;
#pragma unroll
  for (int mi = 0; mi < 4; ++mi) {
#pragma unroll
    for (int ni = 0; ni < 4; ++ni) {
      const long col = n0 + wc * 64 + ni * 16 + l15;
      const float bv2 = bias[col];
#pragma unroll
      for (int j = 0; j < 4; ++j) {
        const long row = m0 + wr * 64 + mi * 16 + lg * 4 + j;
        const float val = acc[mi][ni][j] + bv2;
        if (sel < 2) {
          dq[row * Dc + col] = (f16)val;
        } else {
          const long b = row >> 11, s = row & 2047;
          Vt[(b * Dc + col) * (long)Sc + s] = (f16)val;
        }
      }
    }
  }
}

// MODE 2: dst f32 row-major [M][N], + bias (fc).
// MODE 3: dst f32 row-major [M][N] * scale, batched via blockIdx.z (avg).
template <int MODE>
__global__ __launch_bounds__(256) void gemm128(
    const f16* __restrict__ A, const f16* __restrict__ Bw,
    const float* __restrict__ bias, float* __restrict__ dst,
    int N, int K, long sAz, long sBz, long sDz, float scale) {
  const int tid = threadIdx.x;
  const int lane = tid & 63;
  const int w = tid >> 6;
  const int wr = w >> 1, wc = w & 1;
  const int l15 = lane & 15, lg = lane >> 4;
  const long m0 = (long)blockIdx.x * 128;
  const long n0 = (long)blockIdx.y * 128;
  const f16* Ab = A + (long)blockIdx.z * sAz + m0 * K;
  const f16* Bb = Bw + (long)blockIdx.z * sBz + n0 * K;

  GEMM_CORE(Ab, Bb, K)

  float* dp = dst + (long)blockIdx.z * sDz;
#pragma unroll
  for (int mi = 0; mi < 4; ++mi) {
#pragma unroll
    for (int ni = 0; ni < 4; ++ni) {
      const long col = n0 + wc * 64 + ni * 16 + l15;
      const float bv = (MODE == 3) ? 0.0f : bias[col];
#pragma unroll
      for (int j = 0; j < 4; ++j) {
        const long row = m0 + wr * 64 + mi * 16 + lg * 4 + j;
        const float val = acc[mi][ni][j] + bv;
        dp[row * N + col] = (MODE == 3) ? val * scale : val;
      }
    }
  }
}

// -------- flash attention: 8 waves/block, 128 q-rows, KVBLK=64 --------------
// Swapped QK^T, exp2-domain online softmax with defer-max (T13), O^T = V^T@P^T,
// T14 async staging, T5 setprio, T2 XOR-swizzled LDS, T1 XCD block swizzle.
__global__ __launch_bounds__(512) void attn8(const f16* __restrict__ Q,
                                             const f16* __restrict__ Km,
                                             const f16* __restrict__ Vt,
                                             f16* __restrict__ ctx) {
  const int tid = threadIdx.x;
  const int lane = tid & 63;
  const int w = tid >> 6;              // 0..7
  const int l15 = lane & 15, lg = lane >> 4;
  // T1: 768 blocks = 8 XCD x 96; each XCD owns 6 whole (b,h) K/V panels.
  const int lid = (blockIdx.x & 7) * 96 + (blockIdx.x >> 3);
  const int qt = lid & 15;             // S/128 = 16 q-tiles
  const int h  = (lid >> 4) % Hc;
  const int b  = lid / (16 * Hc);
  const int q0 = qt * 128 + w * 16;

  __shared__ f16 Ks[64 * 64];
  __shared__ f16 Vs[64 * 64];
  __shared__ f16 Ps[8 * 16 * 64];
  char* kb = (char*)Ks;
  char* vb = (char*)Vs;
  char* pb = (char*)Ps + (w << 11);    // per-wave 2KB

  // Q fragment = B-operand of swapped QK: lane holds q-col = l15.
  f16x8 qf[2];
  {
    const f16* qp = Q + ((long)(b * Sc + q0 + l15)) * Dc + h * DKc + lg * 8;
    qf[0] = *reinterpret_cast<const f16x8*>(qp);
    qf[1] = *reinterpret_cast<const f16x8*>(qp + 32);
  }

  const int srow = tid >> 3;           // 0..63 (512 threads)
  const int scolB = (tid & 7) * 16;    // byte col 0..112
  const f16* Kg = Km + (long)(b * Sc) * Dc + h * DKc;    // + kv*Dc + d
  const f16* Vg = Vt + ((long)(b * Dc + h * DKc)) * Sc;  // + dk*Sc + kv

  const float c2 = 0.18033688011f;     // log2(e) / temp, temp = 8
  float m2 = -1e30f, l_run = 0.f;
  f32x4 o[4] = {};

  // prologue: stage tile 0 (swizzled)
  *reinterpret_cast<f16x8*>(kb + SWZ(srow, scolB)) =
      *reinterpret_cast<const f16x8*>(Kg + (long)srow * Dc + scolB / 2);
  *reinterpret_cast<f16x8*>(vb + SWZ(srow, scolB)) =
      *reinterpret_cast<const f16x8*>(Vg + (long)srow * Sc + scolB / 2);
  __syncthreads();

  for (int kv0 = 0; kv0 < Sc; kv0 += 64) {
    const bool pf = (kv0 + 64) < Sc;
    f16x8 kr, vr;
    if (pf) {  // T14: issue next-tile loads early; ds_write after barrier
      kr = *reinterpret_cast<const f16x8*>(Kg + (long)(kv0 + 64 + srow) * Dc + scolB / 2);
      vr = *reinterpret_cast<const f16x8*>(Vg + (long)srow * Sc + kv0 + 64 + scolB / 2);
    }

    // swapped QK^T: sc[t] -> D[kv][q], lane: q = l15, kv = t*16 + lg*4 + j
    f32x4 sc[4];
    __builtin_amdgcn_s_setprio(1);
#pragma unroll
    for (int t = 0; t < 4; ++t) {
      const int row = t * 16 + l15;
      f32x4 s = {};
      s = mfma16(*reinterpret_cast<const f16x8*>(kb + SWZ(row, lg * 16)), qf[0], s);
      s = mfma16(*reinterpret_cast<const f16x8*>(kb + SWZ(row, 64 + lg * 16)), qf[1], s);
      sc[t] = s;
    }
    __builtin_amdgcn_s_setprio(0);

    // online softmax, log2 domain, defer-max (THR = 8 nats = 11.544 bits)
    float mx = sc[0][0];
#pragma unroll
    for (int t = 0; t < 4; ++t)
#pragma unroll
      for (int j = 0; j < 4; ++j) mx = fmaxf(mx, sc[t][j]);
    const float mx2 = mx * c2;
    float al = 1.0f;
    if (!__all(mx2 <= m2 + 11.544f)) {
      float g = fmaxf(mx2, __shfl_xor(mx2, 16));
      g = fmaxf(g, __shfl_xor(g, 32));
      const float mn2 = fmaxf(m2, g);
      al = __builtin_amdgcn_exp2f(m2 - mn2);
      m2 = mn2;
#pragma unroll
      for (int c = 0; c < 4; ++c)
#pragma unroll
        for (int j = 0; j < 4; ++j) o[c][j] *= al;
    }
    float ps = 0.f;
    f16x4 pp[4];
#pragma unroll
    for (int t = 0; t < 4; ++t)
#pragma unroll
      for (int j = 0; j < 4; ++j) {
        float p = __builtin_amdgcn_exp2f(__builtin_fmaf(sc[t][j], c2, -m2));
        pp[t][j] = (f16)p;
        ps += p;
      }
    ps += __shfl_xor(ps, 16);
    ps += __shfl_xor(ps, 32);
    l_run = l_run * al + ps;

    // P^T regs -> Ps (per-wave, swizzled): row q=l15, byte col = t*32 + lg*8
#pragma unroll
    for (int t = 0; t < 4; ++t)
      *reinterpret_cast<f16x4*>(pb + SWZ(l15, t * 32 + lg * 8)) = pp[t];
    asm volatile("s_waitcnt lgkmcnt(0)" ::: "memory");
    __builtin_amdgcn_sched_barrier(0);

    // PV: O^T += V^T @ P^T
    f16x8 pa0 = *reinterpret_cast<const f16x8*>(pb + SWZ(l15, lg * 16));
    f16x8 pa1 = *reinterpret_cast<const f16x8*>(pb + SWZ(l15, 64 + lg * 16));
    __builtin_amdgcn_s_setprio(1);
#pragma unroll
    for (int c = 0; c < 4; ++c) {
      const int row = c * 16 + l15;
      o[c] = mfma16(*reinterpret_cast<const f16x8*>(vb + SWZ(row, lg * 16)), pa0, o[c]);
      o[c] = mfma16(*reinterpret_cast<const f16x8*>(vb + SWZ(row, 64 + lg * 16)), pa1, o[c]);
    }
    __builtin_amdgcn_s_setprio(0);

    if (pf) {
      __syncthreads();  // all waves done reading Ks/Vs
      *reinterpret_cast<f16x8*>(kb + SWZ(srow, scolB)) = kr;
      *reinterpret_cast<f16x8*>(vb + SWZ(srow, scolB)) = vr;
      __syncthreads();  // new tile visible
    }
  }

  // epilogue: o[c][j] = O^T[dk = c*16 + lg*4 + j][q = l15]
  const float inv = 1.0f / l_run;
  f16* cp = ctx + ((long)(b * Sc) + q0 + l15) * Dc + h * DKc;
#pragma unroll
  for (int c = 0; c < 4; ++c) {
    f16x4 ov;
#pragma unroll
    for (int j = 0; j < 4; ++j) ov[j] = (f16)(o[c][j] * inv);
    *reinterpret_cast<f16x4*>(cp + c * 16 + lg * 4) = ov;
  }
}

extern "C" void kernel_launch(void* const* d_in, const int* in_sizes, int n_in,
                              void* d_out, int out_size, void* d_ws, size_t ws_size,
                              hipStream_t stream) {
  (void)in_sizes; (void)n_in; (void)out_size; (void)ws_size;
  const float* z    = (const float*)d_in[0];
  const float* wq_w = (const float*)d_in[1];
  const float* wq_b = (const float*)d_in[2];
  const float* wk_w = (const float*)d_in[3];
  const float* wk_b = (const float*)d_in[4];
  const float* wv_w = (const float*)d_in[5];
  const float* wv_b = (const float*)d_in[6];
  const float* fc_w = (const float*)d_in[7];
  const float* fc_b = (const float*)d_in[8];
  float* out = (float*)d_out;

  char* ws = (char*)d_ws;
  size_t off = 0;
  auto alloc = [&](size_t bytes) -> void* {
    void* p = (void*)(ws + off);
    off += (bytes + 255) & ~(size_t)255;
    return p;
  };
  const size_t zdb = (size_t)Bc * Sc * Dc * sizeof(f16);   // 12.6 MB
  const size_t wdb = (size_t)Dc * Dc * sizeof(f16);        // 1.2 MB
  f16* zb  = (f16*)alloc(zdb);
  f16* wqb = (f16*)alloc(wdb);
  f16* wkb = (f16*)alloc(wdb);
  f16* wvb = (f16*)alloc(wdb);
  f16* fcb = (f16*)alloc(wdb);
  f16* Qb  = (f16*)alloc(zdb);
  f16* Kb  = (f16*)alloc(zdb);
  f16* Vt  = (f16*)alloc(zdb);
  f16* Cx  = zb;  // alias: zb is dead after the QKV projection

  cvt5<<<8448, 256, 0, stream>>>(z, wq_w, wk_w, wv_w, fc_w, zb, wqb, wkb, wvb, fcb);

  dim3 gqkv(Bc * Sc / 128, 18, 1);  // 64 x 18 = 1152 blocks
  gemm_qkv<<<gqkv, 256, 0, stream>>>(zb, wqb, wkb, wvb, wq_b, wk_b, wv_b, Qb, Kb, Vt);

  // avg_weights = (Qfull @ Kfull^T) / (temp*H), temp=8, H=12
  dim3 gavg(Sc / 128, Sc / 128, Bc);  // 16 x 16 x 4
  gemm128<3><<<gavg, 256, 0, stream>>>(Qb, Kb, nullptr, out + (size_t)Bc * Sc * Dc,
                                       Sc, Dc, (long)Sc * Dc, (long)Sc * Dc,
                                       (long)Sc * Sc, 1.0f / 96.0f);

  attn8<<<Bc * Hc * (Sc / 128), 512, 0, stream>>>(Qb, Kb, Vt, Cx);

  dim3 gfc(Bc * Sc / 128, Dc / 128, 1);  // 64 x 6
  gemm128<2><<<gfc, 256, 0, stream>>>(Cx, fcb, fc_b, out, Dc, Dc, 0, 0, 0, 1.f);
}